// Round 2
// baseline (239.795 us; speedup 1.0000x reference)
//
#include <hip/hip_runtime.h>
#include <math.h>

#define NB 32
#define HQ 16
#define DN 128
#define DR 64
#define DQT 192      // DN + DR
#define DV 128
#define PAGE 64
#define MAXP 64
#define SM_SCALE 0.07216878364870322f

// Intra-wave LDS ordering: DS ops are in-order per wave; the waitcnt +
// memory clobber stops compiler reordering and drains outstanding lgkm.
#define WAVE_LDS_FENCE() asm volatile("s_waitcnt lgkmcnt(0)" ::: "memory")

// Transpose q[b][h][c4] (float4 view) -> qT[b][c4][h] so that for a fixed
// c-chunk all 16 heads are 256B-contiguous => scalar-loadable (s_load_dwordx16).
__global__ __launch_bounds__(256)
void q_transpose_kernel(const float* __restrict__ q, float* __restrict__ qT)
{
    int idx = blockIdx.x * 256 + threadIdx.x;            // [0, 32*48*16)
    if (idx >= NB * 48 * HQ) return;
    int h = idx & 15;
    int t = idx >> 4;
    int c4 = t % 48;
    int b = t / 48;
    const float4* q4 = (const float4*)q;
    ((float4*)qT)[idx] = q4[((size_t)b * HQ + h) * 48 + c4];
}

// One wave = one (batch, PP consecutive pages) item. Wave-local softmax via
// shuffles; probs round-trip through a per-wave private 4KB LDS region.
template<int PP>
__global__ __launch_bounds__(256, 2)
void attn_partial_kernel(const float* __restrict__ qT,
                         const float* __restrict__ kn,
                         const float* __restrict__ kr,
                         const float* __restrict__ v,
                         const int* __restrict__ seq_lens,
                         const int* __restrict__ block_table,
                         float* __restrict__ o_part,   // [NB][NS][HQ][DV]
                         float* __restrict__ ml_part)  // [NB][NS][HQ][2]
{
    constexpr int NS = MAXP / PP;          // splits per batch
    const int tid = (int)threadIdx.x;
    const int wave = tid >> 6;
    const int lane = tid & 63;

    const int item = blockIdx.x * 4 + wave;
    const int b = item / NS;
    const int chunk = item % NS;
    const int page0 = chunk * PP;

    const int seq = seq_lens[b];
    if (page0 * PAGE >= seq) return;       // wave-uniform, no barriers anywhere

    __shared__ float p_s[4][PAGE][HQ];     // 16 KB; [wave] regions are private

    const float4* qTb = (const float4*)qT + (size_t)b * 48 * HQ;

    float m_run[HQ], l_run[HQ];
    float4 accv[HQ];
    #pragma unroll
    for (int h = 0; h < HQ; h++) {
        m_run[h] = -INFINITY; l_run[h] = 0.f;
        accv[h] = make_float4(0.f, 0.f, 0.f, 0.f);
    }

    const int tg = lane >> 5;              // token parity group for PV
    const int dq = (lane & 31) * 4;        // d-quad for PV

    #pragma unroll
    for (int pg = 0; pg < PP; pg++) {
        const int page = page0 + pg;
        if (page * PAGE >= seq) break;     // wave-uniform
        const int pid = block_table[b * MAXP + page];
        const bool valid = page * PAGE + lane < seq;

        // ---- scores: lane = token, q broadcast via scalar loads ----
        float s[HQ];
        #pragma unroll
        for (int h = 0; h < HQ; h++) s[h] = 0.f;

        const float4* knp = (const float4*)(kn + ((size_t)pid * PAGE + lane) * DN);
        #pragma unroll 8
        for (int c = 0; c < DN / 4; c++) {
            float4 k4 = knp[c];
            const float4* qc = qTb + c * HQ;           // uniform address
            #pragma unroll
            for (int h = 0; h < HQ; h++) {
                float4 q4 = qc[h];
                s[h] += q4.x * k4.x + q4.y * k4.y + q4.z * k4.z + q4.w * k4.w;
            }
        }
        const float4* krp = (const float4*)(kr + ((size_t)pid * PAGE + lane) * DR);
        #pragma unroll 8
        for (int c = 0; c < DR / 4; c++) {
            float4 k4 = krp[c];
            const float4* qc = qTb + (DN / 4 + c) * HQ;
            #pragma unroll
            for (int h = 0; h < HQ; h++) {
                float4 q4 = qc[h];
                s[h] += q4.x * k4.x + q4.y * k4.y + q4.z * k4.z + q4.w * k4.w;
            }
        }
        #pragma unroll
        for (int h = 0; h < HQ; h++) s[h] = valid ? s[h] * SM_SCALE : -INFINITY;

        // ---- wave-local online softmax ----
        float alpha[HQ];
        #pragma unroll
        for (int h = 0; h < HQ; h++) {
            float m = s[h];
            #pragma unroll
            for (int off = 32; off > 0; off >>= 1) m = fmaxf(m, __shfl_xor(m, off));
            float m_new = fmaxf(m_run[h], m);
            alpha[h] = __expf(m_run[h] - m_new);       // first page: exp(-inf)=0
            m_run[h] = m_new;
            s[h] = __expf(s[h] - m_new);               // invalid lanes -> 0
            float l = s[h];
            #pragma unroll
            for (int off = 32; off > 0; off >>= 1) l += __shfl_xor(l, off);
            l_run[h] = l_run[h] * alpha[h] + l;
        }

        // ---- p -> per-wave LDS (token-major rows) ----
        WAVE_LDS_FENCE();                  // WAR vs previous page's PV reads
        {
            float4* prow = (float4*)(&p_s[wave][lane][0]);
            #pragma unroll
            for (int j = 0; j < 4; j++)
                prow[j] = make_float4(s[4*j+0], s[4*j+1], s[4*j+2], s[4*j+3]);
        }
        WAVE_LDS_FENCE();                  // RAW before PV reads

        // ---- PV: lane = (token-parity, d-quad); p reads are broadcasts ----
        #pragma unroll
        for (int h = 0; h < HQ; h++) {
            accv[h].x *= alpha[h]; accv[h].y *= alpha[h];
            accv[h].z *= alpha[h]; accv[h].w *= alpha[h];
        }
        const float* vp = v + (size_t)pid * PAGE * DV + dq;
        #pragma unroll 4
        for (int t = tg; t < PAGE; t += 2) {
            float4 v4 = *(const float4*)(vp + (size_t)t * DV);
            const float4* prow = (const float4*)(&p_s[wave][t][0]);
            #pragma unroll
            for (int j = 0; j < 4; j++) {
                float4 p4 = prow[j];       // 32-lane broadcast, conflict-free
                accv[4*j+0].x += p4.x * v4.x; accv[4*j+0].y += p4.x * v4.y;
                accv[4*j+0].z += p4.x * v4.z; accv[4*j+0].w += p4.x * v4.w;
                accv[4*j+1].x += p4.y * v4.x; accv[4*j+1].y += p4.y * v4.y;
                accv[4*j+1].z += p4.y * v4.z; accv[4*j+1].w += p4.y * v4.w;
                accv[4*j+2].x += p4.z * v4.x; accv[4*j+2].y += p4.z * v4.y;
                accv[4*j+2].z += p4.z * v4.z; accv[4*j+2].w += p4.z * v4.w;
                accv[4*j+3].x += p4.w * v4.x; accv[4*j+3].y += p4.w * v4.y;
                accv[4*j+3].z += p4.w * v4.z; accv[4*j+3].w += p4.w * v4.w;
            }
        }
    }

    // combine token-parity halves
    #pragma unroll
    for (int h = 0; h < HQ; h++) {
        accv[h].x += __shfl_xor(accv[h].x, 32);
        accv[h].y += __shfl_xor(accv[h].y, 32);
        accv[h].z += __shfl_xor(accv[h].z, 32);
        accv[h].w += __shfl_xor(accv[h].w, 32);
    }

    if (lane < 32) {
        float* op = o_part + ((size_t)(b * NS + chunk) * HQ) * DV + dq;
        #pragma unroll
        for (int h = 0; h < HQ; h++)
            *(float4*)(op + h * DV) = accv[h];
    }
    if (lane == 0) {
        float* ml = ml_part + ((size_t)(b * NS + chunk) * HQ) * 2;
        #pragma unroll
        for (int h = 0; h < HQ; h++) {
            ml[2*h]   = m_run[h];
            ml[2*h+1] = l_run[h];
        }
    }
}

// Merge partials across splits (log-sum-exp combine).
template<int PP>
__global__ __launch_bounds__(128)
void attn_combine_kernel(const float* __restrict__ o_part,
                         const float* __restrict__ ml_part,
                         const int* __restrict__ seq_lens,
                         float* __restrict__ out)
{
    constexpr int NS = MAXP / PP;
    constexpr int SPLIT_T = PP * PAGE;
    const int h = blockIdx.x;
    const int b = blockIdx.y;
    const int d = (int)threadIdx.x;
    const int seq = seq_lens[b];
    int ns = (seq + SPLIT_T - 1) / SPLIT_T;
    if (ns > NS) ns = NS;

    float M = -INFINITY, den = 0.f, acc = 0.f;
    #pragma unroll 4
    for (int s2 = 0; s2 < ns; s2++) {
        const float2 ml = *(const float2*)(ml_part +
                            ((size_t)(b * NS + s2) * HQ + h) * 2);
        float o = o_part[((size_t)(b * NS + s2) * HQ + h) * DV + d];
        float nM = fmaxf(M, ml.x);
        float eo = __expf(M - nM);
        float en = __expf(ml.x - nM);
        acc = acc * eo + o * en;
        den = den * eo + ml.y * en;
        M = nM;
    }
    out[((size_t)b * HQ + h) * DV + d] = acc / den;
}

extern "C" void kernel_launch(void* const* d_in, const int* in_sizes, int n_in,
                              void* d_out, int out_size, void* d_ws, size_t ws_size,
                              hipStream_t stream)
{
    const float* q  = (const float*)d_in[0];
    const float* kn = (const float*)d_in[1];
    const float* kr = (const float*)d_in[2];
    const float* v  = (const float*)d_in[3];
    const int* seq_lens    = (const int*)d_in[4];
    const int* block_table = (const int*)d_in[5];

    const size_t big_need = (size_t)NB * 64 * HQ * DV * 4   // o_part 16 MB
                          + (size_t)NB * 64 * HQ * 2 * 4    // ml 256 KB
                          + (size_t)NB * 48 * HQ * 4 * 4;   // qT 384 KB

    if (ws_size >= big_need) {
        constexpr int PP = 1, NS = MAXP / PP;
        float* o_part  = (float*)d_ws;
        float* ml_part = o_part + (size_t)NB * NS * HQ * DV;
        float* qT      = ml_part + (size_t)NB * NS * HQ * 2;
        q_transpose_kernel<<<(NB*48*HQ + 255)/256, 256, 0, stream>>>(q, qT);
        attn_partial_kernel<PP><<<NB * NS / 4, 256, 0, stream>>>(
            qT, kn, kr, v, seq_lens, block_table, o_part, ml_part);
        attn_combine_kernel<PP><<<dim3(HQ, NB), 128, 0, stream>>>(
            o_part, ml_part, seq_lens, (float*)d_out);
    } else {
        constexpr int PP = 4, NS = MAXP / PP;
        float* o_part  = (float*)d_ws;
        float* ml_part = o_part + (size_t)NB * NS * HQ * DV;
        float* qT      = ml_part + (size_t)NB * NS * HQ * 2;
        q_transpose_kernel<<<(NB*48*HQ + 255)/256, 256, 0, stream>>>(q, qT);
        attn_partial_kernel<PP><<<NB * NS / 4, 256, 0, stream>>>(
            qT, kn, kr, v, seq_lens, block_table, o_part, ml_part);
        attn_combine_kernel<PP><<<dim3(HQ, NB), 128, 0, stream>>>(
            o_part, ml_part, seq_lens, (float*)d_out);
    }
}

// Round 4
// 216.874 us; speedup vs baseline: 1.1057x; 1.1057x over previous
//
#include <hip/hip_runtime.h>
#include <math.h>

#define NB 32
#define HQ 16
#define DN 128
#define DR 64
#define DQ (DN + DR)
#define DV 128
#define PAGE 64
#define MAXP 64
#define SM_SCALE 0.07216878364870322f
#define RS 88   // p_s row stride in f16: 176B -> 16B-aligned frags, 2-way bank alias only

typedef __attribute__((ext_vector_type(8))) _Float16 f16x8;
typedef __attribute__((ext_vector_type(4))) _Float16 f16x4;
typedef __attribute__((ext_vector_type(2))) __fp16   h16x2;  // cvt_pkrtz result type
typedef __attribute__((ext_vector_type(4))) float    f32x4;

union F16x8 { f16x8 v; h16x2 h[4]; };
union F16x4 { f16x4 v; h16x2 h[2]; };

// One wave = (batch b, chunk c); chunk c covers pages {c + j*NSC}. Scores via
// mfma_f32_16x16x32_f16: A = K-tile (16 tok x 32 d), B = q^T (32 d x 16 heads,
// resident in 24 VGPRs for the whole wave). PV: A = V^T frag, B = P from LDS.
// Lane roles: ln = lane&15 (head col for S and PV-D), qd = lane>>4 (quad).
template<int NSC>
__global__ __launch_bounds__(256, 2)
void attn_partial_kernel(const float* __restrict__ q,
                         const float* __restrict__ kn,
                         const float* __restrict__ kr,
                         const float* __restrict__ v,
                         const int* __restrict__ seq_lens,
                         const int* __restrict__ block_table,
                         float* __restrict__ o_part,   // [NB][NSC][HQ][DV]
                         float* __restrict__ ml_part)  // [NB][NSC][HQ][2]
{
    const int tid  = (int)threadIdx.x;
    const int wave = tid >> 6;
    const int lane = tid & 63;
    const int ln   = lane & 15;
    const int qd   = lane >> 4;

    const int item = blockIdx.x * 4 + wave;
    const int b = item / NSC;
    const int c = item % NSC;

    const int seq = seq_lens[b];
    if (c * PAGE >= seq) return;            // wave-uniform; no barriers anywhere

    __shared__ _Float16 p_s[4][HQ][RS];     // per-wave private P buffer (11 KB)

    // q B-frags, all 16 heads x 192 dims, held for the whole wave:
    // bq[kt] element j = q[b][h=ln][kt*32 + qd*8 + j]
    F16x8 bq[6];
    {
        const float* qrow = q + ((size_t)b * HQ + ln) * DQ + qd * 8;
        #pragma unroll
        for (int kt = 0; kt < 6; kt++) {
            float4 x0 = *(const float4*)(qrow + kt * 32);
            float4 x1 = *(const float4*)(qrow + kt * 32 + 4);
            bq[kt].h[0] = __builtin_amdgcn_cvt_pkrtz(x0.x, x0.y);
            bq[kt].h[1] = __builtin_amdgcn_cvt_pkrtz(x0.z, x0.w);
            bq[kt].h[2] = __builtin_amdgcn_cvt_pkrtz(x1.x, x1.y);
            bq[kt].h[3] = __builtin_amdgcn_cvt_pkrtz(x1.z, x1.w);
        }
    }

    float m_run = -INFINITY, l_run = 0.f;
    f32x4 o_acc[8];                          // O^T: rows dv = mt2*16+qd*4+r, col head=ln
    #pragma unroll
    for (int i = 0; i < 8; i++) o_acc[i] = (f32x4){0.f, 0.f, 0.f, 0.f};

    #pragma unroll
    for (int pg = 0; pg < MAXP / NSC; pg++) {
        const int page = c + pg * NSC;
        if (page * PAGE >= seq) break;       // wave-uniform
        const int pid = block_table[b * MAXP + page];

        // ---- scores: S[tok][head], 4 token-tiles x 6 k-tiles ----
        f32x4 sc[4];
        #pragma unroll
        for (int mt = 0; mt < 4; mt++) sc[mt] = (f32x4){0.f, 0.f, 0.f, 0.f};
        const float* knb = kn + (size_t)pid * PAGE * DN;
        const float* krb = kr + (size_t)pid * PAGE * DR;
        #pragma unroll
        for (int mt = 0; mt < 4; mt++) {
            const float* rn = knb + (mt * 16 + ln) * DN + qd * 8;
            const float* rr = krb + (mt * 16 + ln) * DR + qd * 8;
            #pragma unroll
            for (int kt = 0; kt < 6; kt++) {
                const float* src = (kt < 4) ? (rn + kt * 32) : (rr + (kt - 4) * 32);
                float4 x0 = *(const float4*)(src);
                float4 x1 = *(const float4*)(src + 4);
                F16x8 a;
                a.h[0] = __builtin_amdgcn_cvt_pkrtz(x0.x, x0.y);
                a.h[1] = __builtin_amdgcn_cvt_pkrtz(x0.z, x0.w);
                a.h[2] = __builtin_amdgcn_cvt_pkrtz(x1.x, x1.y);
                a.h[3] = __builtin_amdgcn_cvt_pkrtz(x1.z, x1.w);
                sc[mt] = __builtin_amdgcn_mfma_f32_16x16x32_f16(a.v, bq[kt].v, sc[mt], 0, 0, 0);
            }
        }

        // ---- online softmax; head ln state replicated on lanes {ln,+16,+32,+48} ----
        float sv[4][4];
        float smax = -INFINITY;
        #pragma unroll
        for (int mt = 0; mt < 4; mt++)
            #pragma unroll
            for (int r = 0; r < 4; r++) {
                int tok = page * PAGE + mt * 16 + qd * 4 + r;
                float x = (tok < seq) ? sc[mt][r] * SM_SCALE : -INFINITY;
                sv[mt][r] = x;
                smax = fmaxf(smax, x);
            }
        smax = fmaxf(smax, __shfl_xor(smax, 16));
        smax = fmaxf(smax, __shfl_xor(smax, 32));
        const float m_new = fmaxf(m_run, smax);
        const float alpha = __expf(m_run - m_new);   // first page: exp(-inf)=0
        m_run = m_new;
        float lsum = 0.f;
        #pragma unroll
        for (int mt = 0; mt < 4; mt++)
            #pragma unroll
            for (int r = 0; r < 4; r++) {
                float e = __expf(sv[mt][r] - m_new);
                sv[mt][r] = e;
                lsum += e;
            }
        lsum += __shfl_xor(lsum, 16);
        lsum += __shfl_xor(lsum, 32);
        l_run = l_run * alpha + lsum;

        // ---- P -> LDS rows [head][token] (f16); DS ops are wave-ordered ----
        #pragma unroll
        for (int mt = 0; mt < 4; mt++) {
            F16x4 w;
            w.h[0] = __builtin_amdgcn_cvt_pkrtz(sv[mt][0], sv[mt][1]);
            w.h[1] = __builtin_amdgcn_cvt_pkrtz(sv[mt][2], sv[mt][3]);
            *(f16x4*)(&p_s[wave][ln][mt * 16 + qd * 4]) = w.v;
        }

        #pragma unroll
        for (int i = 0; i < 8; i++) o_acc[i] *= alpha;

        // ---- PV: O^T[dv][head] += V^T · P ----
        const float* vb = v + (size_t)pid * PAGE * DV;
        #pragma unroll
        for (int kt2 = 0; kt2 < 2; kt2++) {
            f16x8 pf = *(const f16x8*)(&p_s[wave][ln][kt2 * 32 + qd * 8]);
            const int t0 = kt2 * 32 + qd * 8;
            #pragma unroll
            for (int mt2 = 0; mt2 < 8; mt2++) {
                const float* vc = vb + mt2 * 16 + ln;   // dv column
                F16x8 a;
                a.h[0] = __builtin_amdgcn_cvt_pkrtz(vc[(t0 + 0) * DV], vc[(t0 + 1) * DV]);
                a.h[1] = __builtin_amdgcn_cvt_pkrtz(vc[(t0 + 2) * DV], vc[(t0 + 3) * DV]);
                a.h[2] = __builtin_amdgcn_cvt_pkrtz(vc[(t0 + 4) * DV], vc[(t0 + 5) * DV]);
                a.h[3] = __builtin_amdgcn_cvt_pkrtz(vc[(t0 + 6) * DV], vc[(t0 + 7) * DV]);
                o_acc[mt2] = __builtin_amdgcn_mfma_f32_16x16x32_f16(a.v, pf, o_acc[mt2], 0, 0, 0);
            }
        }
    }

    // ---- epilogue: unnormalized partials ----
    float* op = o_part + ((size_t)(b * NSC + c) * HQ + ln) * DV + qd * 4;
    #pragma unroll
    for (int mt2 = 0; mt2 < 8; mt2++)
        *(f32x4*)(op + mt2 * 16) = o_acc[mt2];
    if (qd == 0) {
        float2* ml = (float2*)(ml_part) + (size_t)(b * NSC + c) * HQ + ln;
        *ml = make_float2(m_run, l_run);
    }
}

// LSE merge across chunks. Two passes: max (independent loads), then weighted sum.
template<int NSC>
__global__ __launch_bounds__(128)
void attn_combine_kernel(const float* __restrict__ o_part,
                         const float* __restrict__ ml_part,
                         const int* __restrict__ seq_lens,
                         float* __restrict__ out)
{
    const int h = blockIdx.x;
    const int b = blockIdx.y;
    const int d = (int)threadIdx.x;
    const int seq = seq_lens[b];
    int npages = (seq + PAGE - 1) / PAGE;
    int ns = npages < NSC ? npages : NSC;

    const float2* mlb = (const float2*)(ml_part) + (size_t)b * NSC * HQ + h;
    float M = -INFINITY;
    #pragma unroll 8
    for (int s2 = 0; s2 < ns; s2++)
        M = fmaxf(M, mlb[(size_t)s2 * HQ].x);

    float acc = 0.f, den = 0.f;
    #pragma unroll 4
    for (int s2 = 0; s2 < ns; s2++) {
        float2 ml = mlb[(size_t)s2 * HQ];
        float e = __expf(ml.x - M);
        float o = o_part[((size_t)(b * NSC + s2) * HQ + h) * DV + d];
        acc += e * o;
        den += e * ml.y;
    }
    out[((size_t)b * HQ + h) * DV + d] = acc / den;
}

extern "C" void kernel_launch(void* const* d_in, const int* in_sizes, int n_in,
                              void* d_out, int out_size, void* d_ws, size_t ws_size,
                              hipStream_t stream)
{
    const float* q  = (const float*)d_in[0];
    const float* kn = (const float*)d_in[1];
    const float* kr = (const float*)d_in[2];
    const float* v  = (const float*)d_in[3];
    const int* seq_lens    = (const int*)d_in[4];
    const int* block_table = (const int*)d_in[5];

    const size_t need32 = (size_t)NB * 32 * HQ * (DV + 2) * 4;   // ~8.3 MB
    if (ws_size >= need32) {
        constexpr int NSC = 32;
        float* o_part  = (float*)d_ws;
        float* ml_part = o_part + (size_t)NB * NSC * HQ * DV;
        attn_partial_kernel<NSC><<<NB * NSC / 4, 256, 0, stream>>>(
            q, kn, kr, v, seq_lens, block_table, o_part, ml_part);
        attn_combine_kernel<NSC><<<dim3(HQ, NB), 128, 0, stream>>>(
            o_part, ml_part, seq_lens, (float*)d_out);
    } else {
        constexpr int NSC = 16;
        float* o_part  = (float*)d_ws;
        float* ml_part = o_part + (size_t)NB * NSC * HQ * DV;
        attn_partial_kernel<NSC><<<NB * NSC / 4, 256, 0, stream>>>(
            q, kn, kr, v, seq_lens, block_table, o_part, ml_part);
        attn_combine_kernel<NSC><<<dim3(HQ, NB), 128, 0, stream>>>(
            o_part, ml_part, seq_lens, (float*)d_out);
    }
}

// Round 5
// 185.133 us; speedup vs baseline: 1.2953x; 1.1714x over previous
//
#include <hip/hip_runtime.h>
#include <math.h>

#define NB 32
#define HQ 16
#define DN 128
#define DR 64
#define DQ (DN + DR)
#define DV 128
#define PAGE 64
#define MAXP 64
#define SM_SCALE 0.07216878364870322f
#define RS 88   // p_s row stride in f16: 176B -> 16B-aligned frags, benign 2-way bank alias

typedef __attribute__((ext_vector_type(8))) _Float16 f16x8;
typedef __attribute__((ext_vector_type(4))) _Float16 f16x4;
typedef __attribute__((ext_vector_type(2))) __fp16   h16x2;  // cvt_pkrtz result type
typedef __attribute__((ext_vector_type(4))) float    f32x4;

union F16x8 { f16x8 v; h16x2 h[4]; };
union F16x4 { f16x4 v; h16x2 h[2]; };

// Intra-wave LDS ordering barrier (DS ops are in-order per wave).
#define WAVE_LDS_FENCE() asm volatile("s_waitcnt lgkmcnt(0)" ::: "memory")

// One BLOCK = one WAVE = (batch b, chunk c); chunk c covers pages {c + j*NSC}.
// Scores: mfma_f32_16x16x32_f16, A = K-tile (16 tok x 32 d), B = q^T (32 d x 16
// heads, wave-resident). PV: A = V^T frag, B = P (LDS round-trip).
// Lane roles: ln = lane&15, qd = lane>>4.
// launch_bounds(64,1): single wave/block, VGPR cap 512 -- registers are free
// here (grid covers the machine), in-flight loads are the scarce resource.
template<int NSC>
__global__ __launch_bounds__(64, 1)
void attn_partial_kernel(const float* __restrict__ q,
                         const float* __restrict__ kn,
                         const float* __restrict__ kr,
                         const float* __restrict__ v,
                         const int* __restrict__ seq_lens,
                         const int* __restrict__ block_table,
                         float* __restrict__ o_part,   // [NB][NSC][HQ][DV]
                         float* __restrict__ ml_part)  // [NB][NSC][HQ][2]
{
    const int lane = (int)threadIdx.x;
    const int ln   = lane & 15;
    const int qd   = lane >> 4;

    const int b = blockIdx.x / NSC;
    const int c = blockIdx.x % NSC;

    const int seq = seq_lens[b];
    if (c * PAGE >= seq) return;            // whole-block exit, scheduler backfills

    __shared__ _Float16 p_s[HQ][RS];        // wave-private P buffer (2.75 KB)

    // q B-frags: bq[kt] element j = q[b][h=ln][kt*32 + qd*8 + j]
    F16x8 bq[6];
    {
        const float* qrow = q + ((size_t)b * HQ + ln) * DQ + qd * 8;
        #pragma unroll
        for (int kt = 0; kt < 6; kt++) {
            float4 x0 = *(const float4*)(qrow + kt * 32);
            float4 x1 = *(const float4*)(qrow + kt * 32 + 4);
            bq[kt].h[0] = __builtin_amdgcn_cvt_pkrtz(x0.x, x0.y);
            bq[kt].h[1] = __builtin_amdgcn_cvt_pkrtz(x0.z, x0.w);
            bq[kt].h[2] = __builtin_amdgcn_cvt_pkrtz(x1.x, x1.y);
            bq[kt].h[3] = __builtin_amdgcn_cvt_pkrtz(x1.z, x1.w);
        }
    }

    float m_run = -INFINITY, l_run = 0.f;
    f32x4 o_acc[8];                          // O^T rows dv = mt2*16+qd*4+r, col head=ln
    #pragma unroll
    for (int i = 0; i < 8; i++) o_acc[i] = (f32x4){0.f, 0.f, 0.f, 0.f};

    #pragma unroll
    for (int pg = 0; pg < MAXP / NSC; pg++) {
        const int page = c + pg * NSC;
        if (page * PAGE >= seq) break;       // wave-uniform
        const int pid = block_table[b * MAXP + page];

        const float* knb = kn + (size_t)pid * PAGE * DN;
        const float* krb = kr + (size_t)pid * PAGE * DR;
        const float* vb  = v  + (size_t)pid * PAGE * DV;

        // ---- scores: S[tok][head], 4 token-tiles x 6 k-tiles ----
        f32x4 sc[4];
        #pragma unroll
        for (int mt = 0; mt < 4; mt++) sc[mt] = (f32x4){0.f, 0.f, 0.f, 0.f};
        #pragma unroll
        for (int mt = 0; mt < 4; mt++) {
            const float* rn = knb + (mt * 16 + ln) * DN + qd * 8;
            const float* rr = krb + (mt * 16 + ln) * DR + qd * 8;
            #pragma unroll
            for (int kt = 0; kt < 6; kt++) {
                const float* src = (kt < 4) ? (rn + kt * 32) : (rr + (kt - 4) * 32);
                float4 x0 = *(const float4*)(src);
                float4 x1 = *(const float4*)(src + 4);
                F16x8 a;
                a.h[0] = __builtin_amdgcn_cvt_pkrtz(x0.x, x0.y);
                a.h[1] = __builtin_amdgcn_cvt_pkrtz(x0.z, x0.w);
                a.h[2] = __builtin_amdgcn_cvt_pkrtz(x1.x, x1.y);
                a.h[3] = __builtin_amdgcn_cvt_pkrtz(x1.z, x1.w);
                sc[mt] = __builtin_amdgcn_mfma_f32_16x16x32_f16(a.v, bq[kt].v, sc[mt], 0, 0, 0);
            }
        }

        // ---- V prefetch (raw fp32, independent of score chain) ----
        // vraw[kt2*8+mt2][j] = V[kt2*32+qd*8+j][mt2*16+ln]
        float vraw[16][8];
        #pragma unroll
        for (int kt2 = 0; kt2 < 2; kt2++) {
            const int t0 = kt2 * 32 + qd * 8;
            #pragma unroll
            for (int mt2 = 0; mt2 < 8; mt2++) {
                const float* vc = vb + mt2 * 16 + ln;
                #pragma unroll
                for (int j = 0; j < 8; j++)
                    vraw[kt2 * 8 + mt2][j] = vc[(size_t)(t0 + j) * DV];
            }
        }

        // ---- online softmax; head ln state replicated on lanes {ln,+16,+32,+48} ----
        float sv[4][4];
        float smax = -INFINITY;
        #pragma unroll
        for (int mt = 0; mt < 4; mt++)
            #pragma unroll
            for (int r = 0; r < 4; r++) {
                int tok = page * PAGE + mt * 16 + qd * 4 + r;
                float x = (tok < seq) ? sc[mt][r] * SM_SCALE : -INFINITY;
                sv[mt][r] = x;
                smax = fmaxf(smax, x);
            }
        smax = fmaxf(smax, __shfl_xor(smax, 16));
        smax = fmaxf(smax, __shfl_xor(smax, 32));
        const float m_new = fmaxf(m_run, smax);
        const float alpha = __expf(m_run - m_new);   // first page: exp(-inf)=0
        m_run = m_new;
        float lsum = 0.f;
        #pragma unroll
        for (int mt = 0; mt < 4; mt++)
            #pragma unroll
            for (int r = 0; r < 4; r++) {
                float e = __expf(sv[mt][r] - m_new);
                sv[mt][r] = e;
                lsum += e;
            }
        lsum += __shfl_xor(lsum, 16);
        lsum += __shfl_xor(lsum, 32);
        l_run = l_run * alpha + lsum;

        // ---- P -> LDS rows [head][token] (f16) ----
        WAVE_LDS_FENCE();                    // WAR vs previous page's reads
        #pragma unroll
        for (int mt = 0; mt < 4; mt++) {
            F16x4 w;
            w.h[0] = __builtin_amdgcn_cvt_pkrtz(sv[mt][0], sv[mt][1]);
            w.h[1] = __builtin_amdgcn_cvt_pkrtz(sv[mt][2], sv[mt][3]);
            *(f16x4*)(&p_s[ln][mt * 16 + qd * 4]) = w.v;
        }
        WAVE_LDS_FENCE();                    // RAW before frag reads

        #pragma unroll
        for (int i = 0; i < 8; i++) o_acc[i] *= alpha;

        // ---- PV: O^T[dv][head] += V^T . P ----
        #pragma unroll
        for (int kt2 = 0; kt2 < 2; kt2++) {
            f16x8 pf = *(const f16x8*)(&p_s[ln][kt2 * 32 + qd * 8]);
            #pragma unroll
            for (int mt2 = 0; mt2 < 8; mt2++) {
                const float* vr = vraw[kt2 * 8 + mt2];
                F16x8 a;
                a.h[0] = __builtin_amdgcn_cvt_pkrtz(vr[0], vr[1]);
                a.h[1] = __builtin_amdgcn_cvt_pkrtz(vr[2], vr[3]);
                a.h[2] = __builtin_amdgcn_cvt_pkrtz(vr[4], vr[5]);
                a.h[3] = __builtin_amdgcn_cvt_pkrtz(vr[6], vr[7]);
                o_acc[mt2] = __builtin_amdgcn_mfma_f32_16x16x32_f16(a.v, pf, o_acc[mt2], 0, 0, 0);
            }
        }
    }

    // ---- epilogue: unnormalized partials ----
    float* op = o_part + ((size_t)(b * NSC + c) * HQ + ln) * DV + qd * 4;
    #pragma unroll
    for (int mt2 = 0; mt2 < 8; mt2++)
        *(f32x4*)(op + mt2 * 16) = o_acc[mt2];
    if (qd == 0) {
        float2* ml = (float2*)(ml_part) + (size_t)(b * NSC + c) * HQ + ln;
        *ml = make_float2(m_run, l_run);
    }
}

// LSE merge across chunks: pass 1 max, pass 2 weighted sum.
template<int NSC>
__global__ __launch_bounds__(128)
void attn_combine_kernel(const float* __restrict__ o_part,
                         const float* __restrict__ ml_part,
                         const int* __restrict__ seq_lens,
                         float* __restrict__ out)
{
    const int h = blockIdx.x;
    const int b = blockIdx.y;
    const int d = (int)threadIdx.x;
    const int seq = seq_lens[b];
    int npages = (seq + PAGE - 1) / PAGE;
    int ns = npages < NSC ? npages : NSC;

    const float2* mlb = (const float2*)(ml_part) + (size_t)b * NSC * HQ + h;
    float M = -INFINITY;
    #pragma unroll 8
    for (int s2 = 0; s2 < ns; s2++)
        M = fmaxf(M, mlb[(size_t)s2 * HQ].x);

    float acc = 0.f, den = 0.f;
    #pragma unroll 4
    for (int s2 = 0; s2 < ns; s2++) {
        float2 ml = mlb[(size_t)s2 * HQ];
        float e = __expf(ml.x - M);
        float o = o_part[((size_t)(b * NSC + s2) * HQ + h) * DV + d];
        acc += e * o;
        den += e * ml.y;
    }
    out[((size_t)b * HQ + h) * DV + d] = acc / den;
}

template<int NSC>
static void launch_all(const float* q, const float* kn, const float* kr,
                       const float* v, const int* seq_lens, const int* block_table,
                       float* d_ws, float* d_out, hipStream_t stream)
{
    float* o_part  = d_ws;
    float* ml_part = o_part + (size_t)NB * NSC * HQ * DV;
    attn_partial_kernel<NSC><<<NB * NSC, 64, 0, stream>>>(
        q, kn, kr, v, seq_lens, block_table, o_part, ml_part);
    attn_combine_kernel<NSC><<<dim3(HQ, NB), 128, 0, stream>>>(
        o_part, ml_part, seq_lens, d_out);
}

extern "C" void kernel_launch(void* const* d_in, const int* in_sizes, int n_in,
                              void* d_out, int out_size, void* d_ws, size_t ws_size,
                              hipStream_t stream)
{
    const float* q  = (const float*)d_in[0];
    const float* kn = (const float*)d_in[1];
    const float* kr = (const float*)d_in[2];
    const float* v  = (const float*)d_in[3];
    const int* seq_lens    = (const int*)d_in[4];
    const int* block_table = (const int*)d_in[5];

    const size_t need64 = (size_t)NB * 64 * HQ * (DV + 2) * 4;   // ~17.0 MB
    const size_t need32 = (size_t)NB * 32 * HQ * (DV + 2) * 4;   // ~8.5 MB

    if (ws_size >= need64)
        launch_all<64>(q, kn, kr, v, seq_lens, block_table, (float*)d_ws, (float*)d_out, stream);
    else if (ws_size >= need32)
        launch_all<32>(q, kn, kr, v, seq_lens, block_table, (float*)d_ws, (float*)d_out, stream);
    else
        launch_all<16>(q, kn, kr, v, seq_lens, block_table, (float*)d_ws, (float*)d_out, stream);
}